// Round 4
// baseline (30.770 us; speedup 1.0000x reference)
//
#include <hip/hip_runtime.h>

// CapsulePooling2D: x (32,64,64,256) f32 -> out (32,32,32,256) f32.
// All work is local to each (batch, 2x2 spatial block). One 64-lane wave
// handles TWO adjacent blocks (lanes 0-31 = block A, 32-63 = block B).
// Channel assignment is DENSE per instruction: lane l owns channels
// {4l..4l+3} and {128+4l..128+4l+3}, so every dwordx4 load/store covers
// contiguous 512 B segments across each 32-lane half (100% coalescing
// density, vs 50% with an 8-consecutive-channels-per-lane layout).

static constexpr float EPS = 1e-7f;

typedef float f32x4 __attribute__((ext_vector_type(4)));  // native vec for nt-store

__device__ __forceinline__ float dot4(const float4& u, const float4& v) {
    return u.x * v.x + u.y * v.y + u.z * v.z + u.w * v.w;
}

__global__ __launch_bounds__(256) void capsule_pool_kernel(
    const float* __restrict__ x, float* __restrict__ out)
{
    constexpr int H = 64, W = 64, C = 256;
    constexpr int HB = H / 2, WB = W / 2;   // 32 x 32 pooled grid

    const int lane   = threadIdx.x & 63;
    const int waveId = threadIdx.x >> 6;
    const int half   = lane >> 5;   // which block of the pair
    const int l      = lane & 31;   // lane within half

    const int pid = blockIdx.x * 4 + waveId;       // block-pair id, 0..16383
    const int jp  = pid & (WB / 2 - 1);            // 0..15 (pair of j's)
    const int i   = (pid >> 4) & (HB - 1);
    const int b   = pid >> 9;
    const int j   = 2 * jp + half;                 // this half's pooled column

    const size_t rowStride = (size_t)W * C;
    // pixel (2i, 2j) base, plus this lane's low-half channel offset
    const float* p = x + ((size_t)b * H + 2 * i) * rowStride
                       + (size_t)(2 * j) * C + 4 * l;

    // 4 pixels x 8 channels: A = ch[4l..4l+3], B = ch[128+4l..128+4l+3]
    const float4 x0A = *(const float4*)(p);
    const float4 x0B = *(const float4*)(p + 128);
    const float4 x1A = *(const float4*)(p + C);
    const float4 x1B = *(const float4*)(p + C + 128);
    const float4 x2A = *(const float4*)(p + rowStride);
    const float4 x2B = *(const float4*)(p + rowStride + 128);
    const float4 x3A = *(const float4*)(p + rowStride + C);
    const float4 x3B = *(const float4*)(p + rowStride + C + 128);

    float s0 = 0.f, s1 = 0.f, s2 = 0.f, s3 = 0.f;  // per-pixel scores (half-uniform)
    float4 aA, aB;                                  // pooled weighted avg (8 ch/lane)

    #pragma unroll
    for (int step = 0; step < 3; ++step) {
        float n0 = 1.f, n1 = 1.f, n2 = 1.f, n3 = 1.f;
        if (step > 0) {
            // normalize_pool_map: within-block softmax-like weights, T=2
            const float m = fmaxf(fmaxf(s0, s1), fmaxf(s2, s3));
            const float e0 = expf((s0 - m) * 0.5f);
            const float e1 = expf((s1 - m) * 0.5f);
            const float e2 = expf((s2 - m) * 0.5f);
            const float e3 = expf((s3 - m) * 0.5f);
            const float inv = 1.f / (0.25f * (e0 + e1 + e2 + e3) + EPS);
            n0 = e0 * inv; n1 = e1 * inv; n2 = e2 * inv; n3 = e3 * inv;
        }
        // a = avg-pool of weighted feature map (this lane's 8 channels)
        aA.x = 0.25f * (n0 * x0A.x + n1 * x1A.x + n2 * x2A.x + n3 * x3A.x);
        aA.y = 0.25f * (n0 * x0A.y + n1 * x1A.y + n2 * x2A.y + n3 * x3A.y);
        aA.z = 0.25f * (n0 * x0A.z + n1 * x1A.z + n2 * x2A.z + n3 * x3A.z);
        aA.w = 0.25f * (n0 * x0A.w + n1 * x1A.w + n2 * x2A.w + n3 * x3A.w);
        aB.x = 0.25f * (n0 * x0B.x + n1 * x1B.x + n2 * x2B.x + n3 * x3B.x);
        aB.y = 0.25f * (n0 * x0B.y + n1 * x1B.y + n2 * x2B.y + n3 * x3B.y);
        aB.z = 0.25f * (n0 * x0B.z + n1 * x1B.z + n2 * x2B.z + n3 * x3B.z);
        aB.w = 0.25f * (n0 * x0B.w + n1 * x1B.w + n2 * x2B.w + n3 * x3B.w);

        if (step < 2) {   // step 3's score update is dead code in the reference
            // squash scale: 1/(1 + ||a||_c + EPS), reduce over this block's 32 lanes
            float ss = dot4(aA, aA) + dot4(aB, aB);
            #pragma unroll
            for (int off = 16; off; off >>= 1) ss += __shfl_xor(ss, off, 32);
            const float scale = 1.f / (1.f + sqrtf(ss) + EPS);

            // score update: score_p += scale * sum_c x[p][c] * a_c
            float p0 = dot4(x0A, aA) + dot4(x0B, aB);
            float p1 = dot4(x1A, aA) + dot4(x1B, aB);
            float p2 = dot4(x2A, aA) + dot4(x2B, aB);
            float p3 = dot4(x3A, aA) + dot4(x3B, aB);
            #pragma unroll
            for (int off = 16; off; off >>= 1) {
                p0 += __shfl_xor(p0, off, 32);
                p1 += __shfl_xor(p1, off, 32);
                p2 += __shfl_xor(p2, off, 32);
                p3 += __shfl_xor(p3, off, 32);
            }
            s0 += p0 * scale; s1 += p1 * scale;
            s2 += p2 * scale; s3 += p3 * scale;
        }
    }

    // out[b][i][j][c] = a_c; nontemporal (never re-read, don't pollute L2/L3)
    float* o = out + (((size_t)b * HB + i) * WB + j) * C + 4 * l;
    const f32x4 vA = {aA.x, aA.y, aA.z, aA.w};
    const f32x4 vB = {aB.x, aB.y, aB.z, aB.w};
    __builtin_nontemporal_store(vA, (f32x4*)o);
    __builtin_nontemporal_store(vB, (f32x4*)(o + 128));
}

extern "C" void kernel_launch(void* const* d_in, const int* in_sizes, int n_in,
                              void* d_out, int out_size, void* d_ws, size_t ws_size,
                              hipStream_t stream) {
    const float* x = (const float*)d_in[0];
    float* out = (float*)d_out;
    // 16384 block-pairs, 4 waves (one pair each) per 256-thread workgroup
    capsule_pool_kernel<<<4096, 256, 0, stream>>>(x, out);
}